// Round 14
// baseline (783.355 us; speedup 1.0000x reference)
//
#include <hip/hip_runtime.h>
#include <stdint.h>

// N=8192 samples, D=4096 statevector dim (fixed by reference)
#define NN 8192
#define DD 4096
#define BK 64           // K-step (two 32x32x32 i8 MFMA in K)
#define NT (DD / BK)    // 64 K-steps
#define NBLK 64         // 8192 / 128
#define LDS_T 16384     // one tile: 64 phys rows x 256 B (128 logical rows, re|im, 16-slot XOR swizzle)
#define LDSBUF 32768    // A tile + B tile
#define NTILE 2080      // upper-tri incl diagonal: 64*65/2

typedef int   i32x4  __attribute__((ext_vector_type(4)));
typedef int   i32x16 __attribute__((ext_vector_type(16)));
typedef float f32x4  __attribute__((ext_vector_type(4)));

#define GLOAD(g, l) __builtin_amdgcn_global_load_lds( \
    (__attribute__((address_space(1))) uint32_t*)(void*)(size_t)(g), \
    (__attribute__((address_space(3))) uint32_t*)(void*)(l), 16, 0, 0)

#define VMW0() asm volatile("s_waitcnt vmcnt(0)" ::: "memory")
#define LGK0() asm volatile("s_waitcnt lgkmcnt(0)" ::: "memory")
#define SBAR() __builtin_amdgcn_s_barrier()

#define MFMA32(a, b, c) __builtin_amdgcn_mfma_i32_32x32x32_i8((a), (b), (c), 0, 0, 0)

// fp32 -> per-row-scaled int8 (planar re8/im8 + scales). Verified round 8.
__global__ __launch_bounds__(256) void convert_kernel(
    const float* __restrict__ re, const float* __restrict__ im,
    char* __restrict__ re8, char* __restrict__ im8, float* __restrict__ scales) {
  __shared__ float red[4];
  const int row = blockIdx.x;
  const int t = threadIdx.x;
  const float4* rr = (const float4*)(re + (size_t)row * DD);
  const float4* ir = (const float4*)(im + (size_t)row * DD);
  float4 rv[4], iv[4];
  float mx = 0.f;
#pragma unroll
  for (int c = 0; c < 4; ++c) {
    rv[c] = rr[t * 4 + c];
    iv[c] = ir[t * 4 + c];
    mx = fmaxf(mx, fmaxf(fmaxf(fabsf(rv[c].x), fabsf(rv[c].y)),
                         fmaxf(fabsf(rv[c].z), fabsf(rv[c].w))));
    mx = fmaxf(mx, fmaxf(fmaxf(fabsf(iv[c].x), fabsf(iv[c].y)),
                         fmaxf(fabsf(iv[c].z), fabsf(iv[c].w))));
  }
#pragma unroll
  for (int off = 32; off > 0; off >>= 1) mx = fmaxf(mx, __shfl_down(mx, off));
  if ((t & 63) == 0) red[t >> 6] = mx;
  __syncthreads();
  mx = fmaxf(fmaxf(red[0], red[1]), fmaxf(red[2], red[3]));
  const float inv = (mx > 1e-30f) ? (127.0f / mx) : 0.0f;
  if (t == 0) scales[row] = mx * (1.0f / 127.0f);

  i32x4 rp, ip;
#pragma unroll
  for (int c = 0; c < 4; ++c) {
    int b0 = (int)rintf(rv[c].x * inv), b1 = (int)rintf(rv[c].y * inv);
    int b2 = (int)rintf(rv[c].z * inv), b3 = (int)rintf(rv[c].w * inv);
    rp[c] = (b0 & 0xFF) | ((b1 & 0xFF) << 8) | ((b2 & 0xFF) << 16) | (b3 << 24);
    b0 = (int)rintf(iv[c].x * inv); b1 = (int)rintf(iv[c].y * inv);
    b2 = (int)rintf(iv[c].z * inv); b3 = (int)rintf(iv[c].w * inv);
    ip[c] = (b0 & 0xFF) | ((b1 & 0xFF) << 8) | ((b2 & 0xFF) << 16) | (b3 << 24);
  }
  ((i32x4*)(re8 + (size_t)row * DD))[t] = rp;
  ((i32x4*)(im8 + (size_t)row * DD))[t] = ip;
}

// 128x128 tile per (bi, bj), bi <= bj. r12 schedule (verified 525 us), but with
// v_mfma_i32_32x32x32_i8 (1.14x i8 OPS rate) and a 256B-row/16-slot LDS swizzle:
// phys row pr (0-63) x 256 B; logical chunk l (0-7: rows 0-63 re0-3/im0-3,
// 8-15: rows 64-127) stored at slot p = l ^ (pr&15). 32-lane read groups span 32
// consecutive rows -> pr&15 aliases only 2-way -> conflict-free (half-wave model).
__global__ __launch_bounds__(256, 2) void gram_kernel(
    const char* __restrict__ re8, const char* __restrict__ im8,
    const float* __restrict__ scales,
    float* __restrict__ wts, float* __restrict__ fidp) {
  __shared__ alignas(16) char lds[2 * LDSBUF];  // 64 KB

  // XCD-aware bijective swizzle (2080 = 8*260)
  const int b = blockIdx.x;
  const int t = (b & 7) * 260 + (b >> 3);

  // t -> (bi, bj), bi <= bj (verified rounds 1-13)
  int bi = (int)(((float)(2 * NBLK + 1) -
                  sqrtf((float)((2 * NBLK + 1) * (2 * NBLK + 1) - 8 * t))) * 0.5f);
  if (bi < 0) bi = 0;
  if (bi > NBLK - 1) bi = NBLK - 1;
  while (bi > 0 && t < bi * NBLK - bi * (bi - 1) / 2) --bi;
  while (t >= (bi + 1) * NBLK - (bi + 1) * bi / 2) ++bi;
  const int bj = bi + (t - (bi * NBLK - bi * (bi - 1) / 2));

  const int brow = bi * 128, bcol = bj * 128;
  const int tid = threadIdx.x;
  const int lane = tid & 63;
  const int wid = tid >> 6;               // 4 waves
  const int wr = wid >> 1, wc = wid & 1;  // 2x2 wave grid, 64x64 out per wave
  const int t16 = tid * 16;

  // ---- staging source (pre-swizzled; LDS dest linear = round*4096 + tid*16) ----
  // thread: pr16 = tid>>4 (phys row base, rounds add 16), slot = tid&15,
  // logical chunk slog = slot ^ pr16; slog: rowhalf = slog>>3 (0: +0, 1: +64 rows),
  // part = (slog>>2)&1 (0=re,1=im), c4 = slog&3 (16B K-chunk).
  const int pr16 = tid >> 4;
  const int slog = (tid & 15) ^ pr16;
  const int rowhalf = slog >> 3;
  const char* smat = ((slog >> 2) & 1) ? im8 : re8;
  const int c4 = slog & 3;
  const char* spA = smat + (size_t)(brow + pr16 + 64 * rowhalf) * DD + c4 * 16;
  const char* spB = smat + (size_t)(bcol + pr16 + 64 * rowhalf) * DD + c4 * 16;
  const size_t r16 = (size_t)16 * DD;   // +16 phys rows per staging round

#define STAGE_A(s, bf) do { const size_t ko = (size_t)(s) * BK;   \
    char* lb_ = lds + (bf) * LDSBUF + t16;                        \
    GLOAD(spA + ko,           lb_);                               \
    GLOAD(spA + ko + r16,     lb_ + 4096);                        \
    GLOAD(spA + ko + 2 * r16, lb_ + 8192);                        \
    GLOAD(spA + ko + 3 * r16, lb_ + 12288); } while (0)
#define STAGE_B(s, bf) do { const size_t ko = (size_t)(s) * BK;   \
    char* lb_ = lds + (bf) * LDSBUF + LDS_T + t16;                \
    GLOAD(spB + ko,           lb_);                               \
    GLOAD(spB + ko + r16,     lb_ + 4096);                        \
    GLOAD(spB + ko + 2 * r16, lb_ + 8192);                        \
    GLOAD(spB + ko + 3 * r16, lb_ + 12288); } while (0)

  // ---- 32x32x32 fragment addressing ----
  // logical row lr = w*64 + m*32 + (lane&31): pr = m*32 + (lane&31), rowhalf = w.
  // re chunk c = kk*2 + hi + 8*w  (im: +4); phys slot = c ^ (pr&15) = c ^ fr15'.
  const int l31 = lane & 31;
  const int hi = lane >> 5;
  const int fr = l31 & 15;               // (m*32+l31)&15 == l31&15
  const int cbA = hi + 8 * wr;
  const int cbB = hi + 8 * wc;
  // byte offsets: (m*32+l31)*256 + slot*16
#define AOFF(m, kk, part) (((m) * 32 + l31) * 256 + (((cbA + (kk) * 2 + (part) * 4) ^ fr) << 4))
#define BOFF(n, kk, part) (16384 + ((n) * 32 + l31) * 256 + (((cbB + (kk) * 2 + (part) * 4) ^ fr) << 4))

  i32x16 acc_g[2][2], acc_x[2][2], acc_y[2][2];   // 192 VGPR
#pragma unroll
  for (int m = 0; m < 2; ++m)
#pragma unroll
    for (int n = 0; n < 2; ++n) {
      acc_g[m][n] = (i32x16)(0);
      acc_x[m][n] = (i32x16)(0);
      acc_y[m][n] = (i32x16)(0);
    }

  // ---- prologue ----
  STAGE_A(0, 0); STAGE_B(0, 0);
  VMW0();
  SBAR();

  for (int s = 0; s < NT; ++s) {
    const char* la = lds + (s & 1) * LDSBUF;
    const int nb = (s & 1) ^ 1;
    const bool pf = (s + 1 < NT);

    if (pf) { STAGE_A(s + 1, nb); STAGE_B(s + 1, nb); }  // 8 loads in flight all step

    i32x4 ar[2][2], ai[2][2];
#pragma unroll
    for (int kk = 0; kk < 2; ++kk)
#pragma unroll
      for (int m = 0; m < 2; ++m) {
        ar[kk][m] = *(const i32x4*)(la + AOFF(m, kk, 0));
        ai[kk][m] = *(const i32x4*)(la + AOFF(m, kk, 1));
      }
#pragma unroll
    for (int n = 0; n < 2; ++n) {
      i32x4 brf[2], bif[2];
#pragma unroll
      for (int kk = 0; kk < 2; ++kk) {
        brf[kk] = *(const i32x4*)(la + BOFF(n, kk, 0));
        bif[kk] = *(const i32x4*)(la + BOFF(n, kk, 1));
      }
      __builtin_amdgcn_s_setprio(1);
#pragma unroll
      for (int kk = 0; kk < 2; ++kk)
#pragma unroll
        for (int m = 0; m < 2; ++m) {
          acc_g[m][n] = MFMA32(ar[kk][m], brf[kk], acc_g[m][n]);
          acc_g[m][n] = MFMA32(ai[kk][m], bif[kk], acc_g[m][n]);
          acc_x[m][n] = MFMA32(ai[kk][m], brf[kk], acc_x[m][n]);
          acc_y[m][n] = MFMA32(ar[kk][m], bif[kk], acc_y[m][n]);
        }
      __builtin_amdgcn_s_setprio(0);
    }

    LGK0();   // own ds_reads done before buffer re-staged next step
    VMW0();   // staging of s+1 landed (issued a full step earlier)
    SBAR();
  }

  // ---- epilogue: 32x32 C/D layout (verified r7): col=lane&31, row=(reg&3)+8*(reg>>2)+4*(lane>>5) ----
  const int gc0 = bcol + wc * 64 + l31;        // + n*32
  const int gr0 = brow + wr * 64 + 4 * hi;     // + m*32 + 8*g + j

#pragma unroll
  for (int m = 0; m < 2; ++m) {
#pragma unroll
    for (int n = 0; n < 2; ++n) {
      const int gc = gc0 + n * 32;
      const float sb = scales[gc];
#pragma unroll
      for (int g = 0; g < 4; ++g) {
        const int grb = gr0 + m * 32 + 8 * g;
        f32x4 fv;
#pragma unroll
        for (int j = 0; j < 4; ++j) {
          const int grow = grb + j;
          const float ss = scales[grow] * sb;
          const float gr = (float)acc_g[m][n][g * 4 + j] * ss;
          const float gi = (float)(acc_x[m][n][g * 4 + j] - acc_y[m][n][g * 4 + j]) * ss;
          fv[j] = gr * gr + gi * gi;
        }
#pragma unroll
        for (int j = 0; j < 4; ++j) {
          const int grow = grb + j;
          const float f = fv[j];
          fidp[(size_t)grow * NN + gc] = f;
          float w = 0.0f;
          if (grow < gc) w = (f >= 0.8f) ? 1.0f : ((f >= 0.5f) ? 0.5f : 0.0f);
          wts[(size_t)grow * NN + gc] = w;
        }
        if (bi != bj) {  // fid symmetric: mirror 4 contiguous rows at transposed addr
          *(f32x4*)(fidp + (size_t)gc * NN + grb) = fv;
        }
      }
    }
  }

  if (bi != bj) {
    // mirror block (bj,bi) of wts is strictly lower-triangular -> zeros
    const f32x4 zz = {0.f, 0.f, 0.f, 0.f};
    for (int i = tid; i < 4096; i += 256) {
      const int r = i >> 5, c4r = i & 31;
      *(f32x4*)(wts + (size_t)(bcol + r) * NN + brow + c4r * 4) = zz;
    }
  }
}

extern "C" void kernel_launch(void* const* d_in, const int* in_sizes, int n_in,
                              void* d_out, int out_size, void* d_ws, size_t ws_size,
                              hipStream_t stream) {
  const float* re = (const float*)d_in[0];
  const float* im = (const float*)d_in[1];
  float* out = (float*)d_out;

  char* re8 = (char*)d_ws;                               // N*D i8
  char* im8 = re8 + (size_t)NN * DD;                     // N*D i8
  float* scales = (float*)(im8 + (size_t)NN * DD);       // N f32  (~67 MB total)

  convert_kernel<<<NN, 256, 0, stream>>>(re, im, re8, im8, scales);
  gram_kernel<<<NTILE, 256, 0, stream>>>(re8, im8, scales, out, out + (size_t)NN * NN);
}

// Round 15
// 604.914 us; speedup vs baseline: 1.2950x; 1.2950x over previous
//
#include <hip/hip_runtime.h>
#include <stdint.h>

// N=8192 samples, D=4096 statevector dim (fixed by reference)
#define NN 8192
#define DD 4096
#define BK 64           // K-step (one i8 MFMA covers K=64)
#define NT (DD / BK)    // 64 K-steps
#define NBLK 64         // 8192 / 128
#define LDS_T 16384     // one tile: 128 rows x 128 B (re[64]|im[64] i8, 8-slot XOR swizzle)
#define LDSBUF 32768    // A tile + B tile
#define NTILE 2080      // upper-tri incl diagonal: 64*65/2

typedef int   i32x4 __attribute__((ext_vector_type(4)));
typedef float f32x4 __attribute__((ext_vector_type(4)));

#define GLOAD(g, l) __builtin_amdgcn_global_load_lds( \
    (__attribute__((address_space(1))) uint32_t*)(void*)(size_t)(g), \
    (__attribute__((address_space(3))) uint32_t*)(void*)(l), 16, 0, 0)

#define VMW0() asm volatile("s_waitcnt vmcnt(0)" ::: "memory")
#define LGK0() asm volatile("s_waitcnt lgkmcnt(0)" ::: "memory")
#define SBAR() __builtin_amdgcn_s_barrier()

#define MFMA_I8(a, b, c) __builtin_amdgcn_mfma_i32_16x16x64_i8((a), (b), (c), 0, 0, 0)

// fp32 -> per-row-scaled int8 (planar re8/im8 + scales). Verified round 8.
__global__ __launch_bounds__(256) void convert_kernel(
    const float* __restrict__ re, const float* __restrict__ im,
    char* __restrict__ re8, char* __restrict__ im8, float* __restrict__ scales) {
  __shared__ float red[4];
  const int row = blockIdx.x;
  const int t = threadIdx.x;
  const float4* rr = (const float4*)(re + (size_t)row * DD);
  const float4* ir = (const float4*)(im + (size_t)row * DD);
  float4 rv[4], iv[4];
  float mx = 0.f;
#pragma unroll
  for (int c = 0; c < 4; ++c) {
    rv[c] = rr[t * 4 + c];
    iv[c] = ir[t * 4 + c];
    mx = fmaxf(mx, fmaxf(fmaxf(fabsf(rv[c].x), fabsf(rv[c].y)),
                         fmaxf(fabsf(rv[c].z), fabsf(rv[c].w))));
    mx = fmaxf(mx, fmaxf(fmaxf(fabsf(iv[c].x), fabsf(iv[c].y)),
                         fmaxf(fabsf(iv[c].z), fabsf(iv[c].w))));
  }
#pragma unroll
  for (int off = 32; off > 0; off >>= 1) mx = fmaxf(mx, __shfl_down(mx, off));
  if ((t & 63) == 0) red[t >> 6] = mx;
  __syncthreads();
  mx = fmaxf(fmaxf(red[0], red[1]), fmaxf(red[2], red[3]));
  const float inv = (mx > 1e-30f) ? (127.0f / mx) : 0.0f;
  if (t == 0) scales[row] = mx * (1.0f / 127.0f);

  i32x4 rp, ip;
#pragma unroll
  for (int c = 0; c < 4; ++c) {
    int b0 = (int)rintf(rv[c].x * inv), b1 = (int)rintf(rv[c].y * inv);
    int b2 = (int)rintf(rv[c].z * inv), b3 = (int)rintf(rv[c].w * inv);
    rp[c] = (b0 & 0xFF) | ((b1 & 0xFF) << 8) | ((b2 & 0xFF) << 16) | (b3 << 24);
    b0 = (int)rintf(iv[c].x * inv); b1 = (int)rintf(iv[c].y * inv);
    b2 = (int)rintf(iv[c].z * inv); b3 = (int)rintf(iv[c].w * inv);
    ip[c] = (b0 & 0xFF) | ((b1 & 0xFF) << 8) | ((b2 & 0xFF) << 16) | (b3 << 24);
  }
  ((i32x4*)(re8 + (size_t)row * DD))[t] = rp;
  ((i32x4*)(im8 + (size_t)row * DD))[t] = ip;
}

// ROUND 12 VERBATIM (verified best: gram 525 us, total 606 us, 0 bank conflicts,
// absmax 6.1e-5). 128x128 tile per (bi, bj), bi <= bj; 4 waves, wave-tile 64x64
// (256 B LDS-read per MFMA = minimal for the sharing topology); 3 accumulators
// g = re.re'+im.im', x = im.re', y = re.im'; fid = (g*s)^2 + ((x-y)*s)^2.
// Additive-wall ledger: MFMA 2612 cy + LDS 2259 cy = 4871 per CU-K-step,
// measured ~4900 -> this config sits on the structural wall.
__global__ __launch_bounds__(256, 2) void gram_kernel(
    const char* __restrict__ re8, const char* __restrict__ im8,
    const float* __restrict__ scales,
    float* __restrict__ wts, float* __restrict__ fidp) {
  __shared__ alignas(16) char lds[2 * LDSBUF];  // 64 KB

  // XCD-aware bijective swizzle (2080 = 8*260)
  const int b = blockIdx.x;
  const int t = (b & 7) * 260 + (b >> 3);

  // t -> (bi, bj), bi <= bj (verified rounds 1-14)
  int bi = (int)(((float)(2 * NBLK + 1) -
                  sqrtf((float)((2 * NBLK + 1) * (2 * NBLK + 1) - 8 * t))) * 0.5f);
  if (bi < 0) bi = 0;
  if (bi > NBLK - 1) bi = NBLK - 1;
  while (bi > 0 && t < bi * NBLK - bi * (bi - 1) / 2) --bi;
  while (t >= (bi + 1) * NBLK - (bi + 1) * bi / 2) ++bi;
  const int bj = bi + (t - (bi * NBLK - bi * (bi - 1) / 2));

  const int brow = bi * 128, bcol = bj * 128;
  const int tid = threadIdx.x;
  const int lane = tid & 63;
  const int wid = tid >> 6;               // 4 waves
  const int wr = wid >> 1, wc = wid & 1;  // 2x2 wave grid, 64x64 out per wave
  const int t16 = tid * 16;

  // ---- staging source (pre-swizzled; LDS dest linear). Verified r8/r12 pattern:
  // LDS row r (128 B): physical 16B slot p holds logical slot p^(r&7);
  // logical slots 0-3 = re k-chunks (16 i8), 4-7 = im. ----
  const int srow = tid >> 3;                    // 0..31 (rounds add 32)
  const int slog = (tid & 7) ^ (srow & 7);
  const char* smat = (slog < 4) ? re8 : im8;
  const int scol = (slog & 3) * 16;
  const char* spA = smat + (size_t)(brow + srow) * DD + scol;
  const char* spB = smat + (size_t)(bcol + srow) * DD + scol;
  const size_t r32 = (size_t)32 * DD;

#define STAGE_A(s, bf) do { const size_t ko = (size_t)(s) * BK;   \
    char* lb_ = lds + (bf) * LDSBUF + t16;                        \
    GLOAD(spA + ko,           lb_);                               \
    GLOAD(spA + ko + r32,     lb_ + 4096);                        \
    GLOAD(spA + ko + 2 * r32, lb_ + 8192);                        \
    GLOAD(spA + ko + 3 * r32, lb_ + 12288); } while (0)
#define STAGE_B(s, bf) do { const size_t ko = (size_t)(s) * BK;   \
    char* lb_ = lds + (bf) * LDSBUF + LDS_T + t16;                \
    GLOAD(spB + ko,           lb_);                               \
    GLOAD(spB + ko + r32,     lb_ + 4096);                        \
    GLOAD(spB + ko + 2 * r32, lb_ + 8192);                        \
    GLOAD(spB + ko + 3 * r32, lb_ + 12288); } while (0)

  // ---- fragment read offsets (verified: slot_phys = kg ^ (row&7), row&7 = fr&7) ----
  const int fr = lane & 15;
  const int kg = lane >> 4;
  const int reslot = (kg ^ (fr & 7)) << 4;   // re frag byte slot; im = ^64
  const int arow = (wr * 64 + fr) * 128;     // + m*2048 (m=0..3), A region @0
  const int brw  = (wc * 64 + fr) * 128;     // + n*2048 (n=0..3), B region @LDS_T

  i32x4 acc_g[4][4], acc_x[4][4], acc_y[4][4];   // 192 VGPR
#pragma unroll
  for (int m = 0; m < 4; ++m)
#pragma unroll
    for (int n = 0; n < 4; ++n) {
      acc_g[m][n] = (i32x4){0, 0, 0, 0};
      acc_x[m][n] = (i32x4){0, 0, 0, 0};
      acc_y[m][n] = (i32x4){0, 0, 0, 0};
    }

  // ---- prologue ----
  STAGE_A(0, 0); STAGE_B(0, 0);
  VMW0();
  SBAR();

  for (int s = 0; s < NT; ++s) {
    const char* la = lds + (s & 1) * LDSBUF;
    const char* lb = la + LDS_T;
    const int nb = (s & 1) ^ 1;
    const bool pf = (s + 1 < NT);

    if (pf) { STAGE_A(s + 1, nb); STAGE_B(s + 1, nb); }  // 8 loads in flight all step

    i32x4 ar[4], ai[4];
#pragma unroll
    for (int m = 0; m < 4; ++m) {
      ar[m] = *(const i32x4*)(la + arow + m * 2048 + reslot);
      ai[m] = *(const i32x4*)(la + arow + m * 2048 + (reslot ^ 64));
    }
#pragma unroll
    for (int n = 0; n < 4; ++n) {
      i32x4 brf = *(const i32x4*)(lb + brw + n * 2048 + reslot);
      i32x4 bif = *(const i32x4*)(lb + brw + n * 2048 + (reslot ^ 64));
      __builtin_amdgcn_s_setprio(1);
#pragma unroll
      for (int m = 0; m < 4; ++m) {
        acc_g[m][n] = MFMA_I8(ar[m], brf, acc_g[m][n]);
        acc_g[m][n] = MFMA_I8(ai[m], bif, acc_g[m][n]);
        acc_x[m][n] = MFMA_I8(ai[m], brf, acc_x[m][n]);
        acc_y[m][n] = MFMA_I8(ar[m], bif, acc_y[m][n]);
      }
      __builtin_amdgcn_s_setprio(0);
    }

    LGK0();   // own ds_reads done before buffer re-staged next step
    VMW0();   // staging of s+1 landed (issued a full step earlier)
    SBAR();
  }

  // ---- epilogue: 16x16 C/D layout (verified): col=lane&15, row=(lane>>4)*4+reg ----
  const int grow0 = brow + wr * 64 + kg * 4;  // + m*16 + j
  const int gcol0 = bcol + wc * 64 + fr;      // + n*16

#pragma unroll
  for (int m = 0; m < 4; ++m) {
#pragma unroll
    for (int n = 0; n < 4; ++n) {
      const int gc = gcol0 + n * 16;
      const float sb = scales[gc];
      f32x4 fv;
#pragma unroll
      for (int j = 0; j < 4; ++j) {
        const int grow = grow0 + m * 16 + j;
        const float ss = scales[grow] * sb;
        const float gr = (float)acc_g[m][n][j] * ss;
        const float gi = (float)(acc_x[m][n][j] - acc_y[m][n][j]) * ss;
        fv[j] = gr * gr + gi * gi;
      }
#pragma unroll
      for (int j = 0; j < 4; ++j) {
        const int grow = grow0 + m * 16 + j;
        const float f = fv[j];
        fidp[(size_t)grow * NN + gc] = f;
        float w = 0.0f;
        if (grow < gc) w = (f >= 0.8f) ? 1.0f : ((f >= 0.5f) ? 0.5f : 0.0f);
        wts[(size_t)grow * NN + gc] = w;
      }
      if (bi != bj) {  // fid symmetric: mirror 4 contiguous rows at transposed addr
        *(f32x4*)(fidp + (size_t)gc * NN + grow0 + m * 16) = fv;
      }
    }
  }

  if (bi != bj) {
    // mirror block (bj,bi) of wts is strictly lower-triangular -> zeros
    const f32x4 zz = {0.f, 0.f, 0.f, 0.f};
    for (int i = tid; i < 4096; i += 256) {
      const int r = i >> 5, c4 = i & 31;
      *(f32x4*)(wts + (size_t)(bcol + r) * NN + brow + c4 * 4) = zz;
    }
  }
}

extern "C" void kernel_launch(void* const* d_in, const int* in_sizes, int n_in,
                              void* d_out, int out_size, void* d_ws, size_t ws_size,
                              hipStream_t stream) {
  const float* re = (const float*)d_in[0];
  const float* im = (const float*)d_in[1];
  float* out = (float*)d_out;

  char* re8 = (char*)d_ws;                               // N*D i8
  char* im8 = re8 + (size_t)NN * DD;                     // N*D i8
  float* scales = (float*)(im8 + (size_t)NN * DD);       // N f32  (~67 MB total)

  convert_kernel<<<NN, 256, 0, stream>>>(re, im, re8, im8, scales);
  gram_kernel<<<NTILE, 256, 0, stream>>>(re8, im8, scales, out, out + (size_t)NN * NN);
}